// Round 1
// baseline (244.946 us; speedup 1.0000x reference)
//
#include <hip/hip_runtime.h>

// RefLocal: 5x5 windowed dot-product attention, fp32.
// B=8 H=96 W=96 C=192 V=96. One 8x8 pixel tile per 64-thread block.
// Halo (12x12) chunks of 16 channels staged in LDS (stride 20 floats to
// spread banks). 25 logits per thread in VGPRs, in-register softmax,
// then value accumulation in 16-float chunks.

#define BATCH 8
#define HH 96
#define WW 96
#define CH 192
#define VV 96
#define KS 5
#define PAD 2
#define TH 8
#define TW 8
#define HT (TH + 2 * PAD) // 12
#define WT (TW + 2 * PAD) // 12
#define CC 16             // channel chunk
#define SP 20             // LDS per-pixel stride in floats (16 data + 4 pad)

__global__ __launch_bounds__(64) void reflocal_kernel(
    const float* __restrict__ qry, const float* __restrict__ key,
    const float* __restrict__ val, float* __restrict__ out) {
  // XCD-locality swizzle: hardware round-robins blockIdx across 8 XCDs;
  // remap so each XCD gets one contiguous image (144 tiles = 1 batch).
  int braw = blockIdx.x;
  int L = (braw & 7) * 144 + (braw >> 3); // gridDim.x == 1152
  int bb = L / 144;
  int t2 = L - bb * 144;
  int tyy = t2 / 12;
  int txx = t2 - tyy * 12;
  int h0 = tyy * TH, w0 = txx * TW;

  int tid = threadIdx.x;
  int ty = tid >> 3, tx = tid & 7;
  int h = h0 + ty, w = w0 + tx;

  __shared__ float s[HT * WT * SP]; // 144 * 20 * 4B = 11.52 KB

  float lg[25];
#pragma unroll
  for (int o = 0; o < 25; ++o) lg[o] = 0.f;

  const float* qbase = qry + (size_t)((bb * HH + h) * WW + w) * CH;

  // ---- Phase 1: logits over C in chunks of 16 ----
  for (int c0 = 0; c0 < CH; c0 += CC) {
    __syncthreads(); // previous chunk's readers done before overwrite
    // stage key halo chunk: 144 pixels x 4 float4 = 576 quads, 9 per thread
    for (int t = tid; t < HT * WT * (CC / 4); t += 64) {
      int p = t >> 2, q = t & 3;
      int ry = p / WT, rx = p - ry * WT;
      int hh = h0 - PAD + ry, ww = w0 - PAD + rx;
      float4 v4 = make_float4(0.f, 0.f, 0.f, 0.f);
      if ((unsigned)hh < HH && (unsigned)ww < WW) {
        v4 = *(const float4*)(key + (size_t)((bb * HH + hh) * WW + ww) * CH +
                              c0 + q * 4);
      }
      *(float4*)(&s[p * SP + q * 4]) = v4;
    }
    __syncthreads();

    float m[CC];
#pragma unroll
    for (int q = 0; q < CC / 4; ++q) {
      float4 v4 = *(const float4*)(qbase + c0 + q * 4);
      m[q * 4 + 0] = v4.x; m[q * 4 + 1] = v4.y;
      m[q * 4 + 2] = v4.z; m[q * 4 + 3] = v4.w;
    }
#pragma unroll
    for (int i = 0; i < KS; ++i) {
#pragma unroll
      for (int j = 0; j < KS; ++j) {
        const float* sp = &s[((ty + i) * WT + tx + j) * SP];
        float acc = 0.f;
#pragma unroll
        for (int q = 0; q < CC / 4; ++q) {
          float4 v4 = *(const float4*)(sp + q * 4);
          acc += m[q * 4 + 0] * v4.x + m[q * 4 + 1] * v4.y +
                 m[q * 4 + 2] * v4.z + m[q * 4 + 3] * v4.w;
        }
        lg[i * 5 + j] += acc;
      }
    }
  }

  // ---- softmax over 25 (zero-padded halo already contributed logit 0,
  //      matching TF SAME-padding semantics of the reference) ----
  float mx = lg[0];
#pragma unroll
  for (int o = 1; o < 25; ++o) mx = fmaxf(mx, lg[o]);
  float sum = 0.f;
#pragma unroll
  for (int o = 0; o < 25; ++o) {
    lg[o] = __expf(lg[o] - mx);
    sum += lg[o];
  }
  float inv = 1.f / sum;
#pragma unroll
  for (int o = 0; o < 25; ++o) lg[o] *= inv;

  // ---- Phase 2: values over V in chunks of 16 ----
  float* obase = out + (size_t)((bb * HH + h) * WW + w) * VV;
  for (int v0 = 0; v0 < VV; v0 += CC) {
    __syncthreads();
    for (int t = tid; t < HT * WT * (CC / 4); t += 64) {
      int p = t >> 2, q = t & 3;
      int ry = p / WT, rx = p - ry * WT;
      int hh = h0 - PAD + ry, ww = w0 - PAD + rx;
      float4 v4 = make_float4(0.f, 0.f, 0.f, 0.f);
      if ((unsigned)hh < HH && (unsigned)ww < WW) {
        v4 = *(const float4*)(val + (size_t)((bb * HH + hh) * WW + ww) * VV +
                              v0 + q * 4);
      }
      *(float4*)(&s[p * SP + q * 4]) = v4;
    }
    __syncthreads();

    float acc[CC];
#pragma unroll
    for (int v = 0; v < CC; ++v) acc[v] = 0.f;
#pragma unroll
    for (int i = 0; i < KS; ++i) {
#pragma unroll
      for (int j = 0; j < KS; ++j) {
        const float* sp = &s[((ty + i) * WT + tx + j) * SP];
        float a = lg[i * 5 + j];
#pragma unroll
        for (int q = 0; q < CC / 4; ++q) {
          float4 v4 = *(const float4*)(sp + q * 4);
          acc[q * 4 + 0] += a * v4.x;
          acc[q * 4 + 1] += a * v4.y;
          acc[q * 4 + 2] += a * v4.z;
          acc[q * 4 + 3] += a * v4.w;
        }
      }
    }
#pragma unroll
    for (int q = 0; q < CC / 4; ++q) {
      *(float4*)(obase + v0 + q * 4) =
          make_float4(acc[q * 4 + 0], acc[q * 4 + 1], acc[q * 4 + 2],
                      acc[q * 4 + 3]);
    }
  }
}

extern "C" void kernel_launch(void* const* d_in, const int* in_sizes, int n_in,
                              void* d_out, int out_size, void* d_ws,
                              size_t ws_size, hipStream_t stream) {
  const float* qry = (const float*)d_in[0]; // main [B,H,W,C]
  const float* key = (const float*)d_in[1]; // ref  [B,H,W,C]
  const float* val = (const float*)d_in[2]; // ref_value [B,H,W,V]
  float* out = (float*)d_out;               // [B,H,W,V]

  dim3 grid(BATCH * (HH / TH) * (WW / TW)); // 8 * 12 * 12 = 1152
  dim3 block(64);
  reflocal_kernel<<<grid, block, 0, stream>>>(qry, key, val, out);
}